// Round 1
// baseline (897.083 us; speedup 1.0000x reference)
//
#include <hip/hip_runtime.h>
#include <math.h>

#define N_NODES 1024
#define IN_CH   1433
#define HID     16
#define OUT_CH  7
#define N_EDGES 4096
#define E_TOT   5120   // N_EDGES + N_NODES (self loops)
#define N_TE    5119   // E_TOT - 1 (embedded series length)

// psi(x) for x >= 1 (integer-valued counts). Recurrence to x>=6 then asymptotic.
__device__ __forceinline__ float digammaf_dev(float x) {
    float r = 0.0f;
    while (x < 6.0f) { r -= 1.0f / x; x += 1.0f; }
    float inv  = 1.0f / x;
    float inv2 = inv * inv;
    r += logf(x) - 0.5f * inv
       - inv2 * (1.0f/12.0f - inv2 * (1.0f/120.0f - inv2 * (1.0f/252.0f)));
    return r;
}

// h1[r][o] = sum_k x[r][k] * W1[o][k] + b1[o].  One block per row.
__global__ __launch_bounds__(256) void gemm1_kernel(
    const float* __restrict__ x, const float* __restrict__ W1,
    const float* __restrict__ b1, float* __restrict__ h1) {
    __shared__ float xrow[IN_CH];
    const int r = blockIdx.x;
    const float* xr = x + (size_t)r * IN_CH;
    for (int k = threadIdx.x; k < IN_CH; k += 256) xrow[k] = xr[k];
    __syncthreads();
    const int o = threadIdx.x >> 4;   // 0..15 output channel
    const int g = threadIdx.x & 15;   // 0..15 lane in group
    const float* w = W1 + o * IN_CH;
    float s = 0.0f;
    for (int k = g; k < IN_CH; k += 16) s += xrow[k] * w[k];
    #pragma unroll
    for (int m = 8; m >= 1; m >>= 1) s += __shfl_xor(s, m, 16);
    if (g == 0) h1[r * HID + o] = s + b1[o];
}

// cnt[d] += 1 per incident edge (incl. self loop)
__global__ void cnt_kernel(const int* __restrict__ ei, float* __restrict__ cnt) {
    int e = blockIdx.x * blockDim.x + threadIdx.x;
    if (e >= E_TOT) return;
    int d = (e < N_EDGES) ? ei[N_EDGES + e] : (e - N_EDGES);
    atomicAdd(&cnt[d], 1.0f);
}

// KSG TE per channel. grid = (ceil(N_TE/256), C). Sequences staged in LDS.
template <int C>
__global__ __launch_bounds__(256) void te_kernel(
    const float* __restrict__ h, const int* __restrict__ ei,
    float* __restrict__ tes_accum) {
    __shared__ float sx[N_TE];    // x_t  = h[dst[t]][c], t < N_TE
    __shared__ float sy[E_TOT];   // xj_t = h[src[t]][c], full length (y=sy[t], z=sy[t+1])
    __shared__ float wsum[4];
    const int c = blockIdx.y;
    for (int e = threadIdx.x; e < E_TOT; e += 256) {
        int s = (e < N_EDGES) ? ei[e] : (e - N_EDGES);
        sy[e] = h[s * C + c];
        if (e < N_TE) {
            int d = (e < N_EDGES) ? ei[N_EDGES + e] : (e - N_EDGES);
            sx[e] = h[d * C + c];
        }
    }
    __syncthreads();

    const int i = blockIdx.x * blockDim.x + threadIdx.x;
    float local = 0.0f;
    if (i < N_TE) {
        const float xi = sx[i], yi = sy[i], zi = sy[i + 1];
        // pass 1: eps_i = min_{j!=i} max(|dx|,|dy|,|dz|)
        float eps = INFINITY;
        float syj = sy[0];
        #pragma unroll 4
        for (int j = 0; j < N_TE; ++j) {
            float syj1 = sy[j + 1];
            float dx = fabsf(xi - sx[j]);
            float dy = fabsf(yi - syj);
            float dz = fabsf(zi - syj1);
            float dj = fmaxf(fmaxf(dx, dy), dz);
            if (j != i) eps = fminf(eps, dj);
            syj = syj1;
        }
        // pass 2: strict-< neighbor counts (diagonal included; cancels the +1 in psi(n+1))
        int ny = 0, nxy = 0, nyz = 0;
        syj = sy[0];
        #pragma unroll 4
        for (int j = 0; j < N_TE; ++j) {
            float syj1 = sy[j + 1];
            float dx = fabsf(xi - sx[j]);
            float dy = fabsf(yi - syj);
            float dz = fabsf(zi - syj1);
            ny  += (dy < eps) ? 1 : 0;
            nxy += (fmaxf(dx, dy) < eps) ? 1 : 0;
            nyz += (fmaxf(dy, dz) < eps) ? 1 : 0;
            syj = syj1;
        }
        local = digammaf_dev((float)ny) - digammaf_dev((float)nxy)
              - digammaf_dev((float)nyz);
    }
    // block reduce -> atomicAdd
    #pragma unroll
    for (int m = 32; m >= 1; m >>= 1) local += __shfl_xor(local, m, 64);
    if ((threadIdx.x & 63) == 0) wsum[threadIdx.x >> 6] = local;
    __syncthreads();
    if (threadIdx.x == 0)
        atomicAdd(&tes_accum[c], wsum[0] + wsum[1] + wsum[2] + wsum[3]);
}

// msg = sigmoid(te_c * h[src][c]); segment-sum into sums[dst][c]
template <int C>
__global__ void agg_kernel(const float* __restrict__ h, const int* __restrict__ ei,
                           const float* __restrict__ tes_accum, float half_scale,
                           float* __restrict__ sums) {
    int idx = blockIdx.x * blockDim.x + threadIdx.x;
    if (idx >= E_TOT * C) return;
    int e = idx / C, c = idx % C;
    int s = (e < N_EDGES) ? ei[e] : (e - N_EDGES);
    int d = (e < N_EDGES) ? ei[N_EDGES + e] : (e - N_EDGES);
    float te = (-0.57721566490153286f + tes_accum[c] * (1.0f / (float)N_TE)) * half_scale;
    float xj = h[s * C + c];
    float m = 1.0f / (1.0f + expf(-te * xj));
    atomicAdd(&sums[d * C + c], m);
}

// layer-1 epilogue: mean + relu
__global__ void fin1_kernel(const float* __restrict__ sums, const float* __restrict__ cnt,
                            float* __restrict__ h1a) {
    int idx = blockIdx.x * blockDim.x + threadIdx.x;
    if (idx >= N_NODES * HID) return;
    int v = idx / HID;
    float val = sums[idx] / fmaxf(cnt[v], 1.0f);
    h1a[idx] = fmaxf(val, 0.0f);
}

// h2 = h1a @ W2^T + b2
__global__ void gemm2_kernel(const float* __restrict__ h1a, const float* __restrict__ W2,
                             const float* __restrict__ b2, float* __restrict__ h2) {
    int idx = blockIdx.x * blockDim.x + threadIdx.x;
    if (idx >= N_NODES * OUT_CH) return;
    int v = idx / OUT_CH, o = idx % OUT_CH;
    float s = b2[o];
    #pragma unroll
    for (int k = 0; k < HID; ++k) s += h1a[v * HID + k] * W2[o * HID + k];
    h2[idx] = s;
}

// layer-2 epilogue: mean + log_softmax
__global__ void fin2_kernel(const float* __restrict__ sums2, const float* __restrict__ cnt,
                            float* __restrict__ out) {
    int v = blockIdx.x * blockDim.x + threadIdx.x;
    if (v >= N_NODES) return;
    float c = fmaxf(cnt[v], 1.0f);
    float vals[OUT_CH];
    float mx = -INFINITY;
    #pragma unroll
    for (int o = 0; o < OUT_CH; ++o) {
        vals[o] = sums2[v * OUT_CH + o] / c;
        mx = fmaxf(mx, vals[o]);
    }
    float se = 0.0f;
    #pragma unroll
    for (int o = 0; o < OUT_CH; ++o) se += expf(vals[o] - mx);
    float lse = mx + logf(se);
    #pragma unroll
    for (int o = 0; o < OUT_CH; ++o) out[v * OUT_CH + o] = vals[o] - lse;
}

extern "C" void kernel_launch(void* const* d_in, const int* in_sizes, int n_in,
                              void* d_out, int out_size, void* d_ws, size_t ws_size,
                              hipStream_t stream) {
    const float* x  = (const float*)d_in[0];
    const int*   ei = (const int*)  d_in[1];
    const float* W1 = (const float*)d_in[2];
    const float* b1 = (const float*)d_in[3];
    const float* W2 = (const float*)d_in[4];
    const float* b2 = (const float*)d_in[5];
    float* out = (float*)d_out;

    // workspace layout (floats)
    float* w     = (float*)d_ws;
    float* h1    = w;              // 16384
    float* tes1  = w + 16384;      // 16
    float* sums1 = w + 16400;      // 16384
    float* cnt   = w + 32784;      // 1024
    float* h1a   = w + 33808;      // 16384
    float* h2    = w + 50192;      // 7168
    float* tes2  = w + 57360;      // 16 (padded)
    float* sums2 = w + 57376;      // 7168
    const size_t ws_used = (size_t)(57376 + 7168) * sizeof(float);

    hipMemsetAsync(d_ws, 0, ws_used, stream);

    gemm1_kernel<<<N_NODES, 256, 0, stream>>>(x, W1, b1, h1);
    cnt_kernel<<<(E_TOT + 255) / 256, 256, 0, stream>>>(ei, cnt);

    const int te_blocks = (N_TE + 255) / 256;  // 20
    te_kernel<HID><<<dim3(te_blocks, HID), 256, 0, stream>>>(h1, ei, tes1);
    agg_kernel<HID><<<(E_TOT * HID + 255) / 256, 256, 0, stream>>>(h1, ei, tes1, 1.0f, sums1);
    fin1_kernel<<<(N_NODES * HID + 255) / 256, 256, 0, stream>>>(sums1, cnt, h1a);

    gemm2_kernel<<<(N_NODES * OUT_CH + 255) / 256, 256, 0, stream>>>(h1a, W2, b2, h2);
    te_kernel<OUT_CH><<<dim3(te_blocks, OUT_CH), 256, 0, stream>>>(h2, ei, tes2);
    agg_kernel<OUT_CH><<<(E_TOT * OUT_CH + 255) / 256, 256, 0, stream>>>(h2, ei, tes2, 0.5f, sums2);
    fin2_kernel<<<(N_NODES + 255) / 256, 256, 0, stream>>>(sums2, cnt, out);
}

// Round 2
// 341.390 us; speedup vs baseline: 2.6277x; 2.6277x over previous
//
#include <hip/hip_runtime.h>
#include <math.h>
#include <float.h>

#define N_NODES 1024
#define IN_CH   1433
#define HID     16
#define OUT_CH  7
#define N_EDGES 4096
#define E_TOT   5120   // N_EDGES + N_NODES (self loops)
#define N_TE    5119   // E_TOT - 1 (embedded series length)
#define CHUNK   512    // j-chunk per block
#define NCH     10     // E_TOT / CHUNK (slot 5119 is a padded/neutralized pair)
#define IB      20     // ceil(N_TE / 256)
#define N_TEP   5120   // pitch for per-i arrays
#define SEQP    5136   // pitch for staged sequences (16B-aligned rows)
#define BIGF    1e30f

// psi(x) for integer-valued x >= 1. Recurrence to x>=6 then asymptotic.
__device__ __forceinline__ float digammaf_dev(float x) {
    float r = 0.0f;
    while (x < 6.0f) { r -= 1.0f / x; x += 1.0f; }
    float inv  = 1.0f / x;
    float inv2 = inv * inv;
    r += logf(x) - 0.5f * inv
       - inv2 * (1.0f/12.0f - inv2 * (1.0f/120.0f - inv2 * (1.0f/252.0f)));
    return r;
}

// h1[r][o] = sum_k x[r][k] * W1[o][k] + b1[o].  One block per row.
__global__ __launch_bounds__(256) void gemm1_kernel(
    const float* __restrict__ x, const float* __restrict__ W1,
    const float* __restrict__ b1, float* __restrict__ h1) {
    __shared__ float xrow[IN_CH];
    const int r = blockIdx.x;
    const float* xr = x + (size_t)r * IN_CH;
    for (int k = threadIdx.x; k < IN_CH; k += 256) xrow[k] = xr[k];
    __syncthreads();
    const int o = threadIdx.x >> 4;
    const int g = threadIdx.x & 15;
    const float* w = W1 + o * IN_CH;
    float s = 0.0f;
    for (int k = g; k < IN_CH; k += 16) s += xrow[k] * w[k];
    #pragma unroll
    for (int m = 8; m >= 1; m >>= 1) s += __shfl_xor(s, m, 16);
    if (g == 0) h1[r * HID + o] = s + b1[o];
}

// degree count per dst (incl. self loop)
__global__ void cnt_kernel(const int* __restrict__ ei, float* __restrict__ cnt) {
    int e = blockIdx.x * blockDim.x + threadIdx.x;
    if (e >= E_TOT) return;
    int d = (e < N_EDGES) ? ei[N_EDGES + e] : (e - N_EDGES);
    atomicAdd(&cnt[d], 1.0f);
}

// Build per-channel gathered sequences with sentinels:
//   seqx[c][t] = h[dst[t]][c] for t<N_TE, BIG at t=N_TE (pad pair slot)
//   seqy[c][t] = h[src[t]][c] for t<E_TOT, BIG at t=E_TOT (z of pad slot)
template <int C>
__global__ void seq_build_kernel(const float* __restrict__ h, const int* __restrict__ ei,
                                 float* __restrict__ seqx, float* __restrict__ seqy) {
    int t = blockIdx.x * blockDim.x + threadIdx.x;
    if (t > E_TOT) return;
    int s = 0, d = 0;
    if (t < E_TOT) s = (t < N_EDGES) ? ei[t] : t - N_EDGES;
    if (t < N_TE)  d = (t < N_EDGES) ? ei[N_EDGES + t] : t - N_EDGES;
    #pragma unroll
    for (int c = 0; c < C; ++c) {
        seqy[c * SEQP + t] = (t < E_TOT) ? h[s * C + c] : BIGF;
        if (t <= N_TE) seqx[c * SEQP + t] = (t < N_TE) ? h[d * C + c] : BIGF;
    }
}

__global__ void eps_init_kernel(float* __restrict__ eps, int n) {
    int i = blockIdx.x * blockDim.x + threadIdx.x;
    if (i < n) eps[i] = FLT_MAX;
}

// Pass 1: partial eps over one j-chunk; combine via float-as-uint atomicMin.
// grid = (IB, NCH, C)
__global__ __launch_bounds__(256) void te_eps_kernel(
    const float* __restrict__ seqx, const float* __restrict__ seqy,
    unsigned int* __restrict__ eps) {
    __shared__ __align__(16) float sxs[CHUNK];
    __shared__ __align__(16) float sys[CHUNK + 8];
    const int ib = blockIdx.x, k = blockIdx.y, c = blockIdx.z;
    const int j0 = k * CHUNK;
    const float* qx = seqx + c * SEQP + j0;
    const float* qy = seqy + c * SEQP + j0;
    for (int l = threadIdx.x; l < CHUNK; l += 256) sxs[l] = qx[l];
    for (int l = threadIdx.x; l < CHUNK + 8; l += 256) sys[l] = (l <= CHUNK) ? qy[l] : BIGF;
    __syncthreads();

    const int i = ib * 256 + threadIdx.x;           // i==N_TE (5119) is discarded
    const float xi = seqx[c * SEQP + i];
    const float yi = seqy[c * SEQP + i];
    const float zi = seqy[c * SEQP + i + 1];

    float e0 = BIGF, e1 = BIGF, e2 = BIGF, e3 = BIGF;
    float4 cur = *(const float4*)sys;
    if (k == (ib >> 1)) {
        // this chunk contains each thread's diagonal j==i
        for (int jg = 0; jg < CHUNK; jg += 4) {
            float4 nxt = *(const float4*)(sys + jg + 4);
            float4 vx  = *(const float4*)(sxs + jg);
            int jb = j0 + jg;
            float d0 = fmaxf(fmaxf(fabsf(xi - vx.x), fabsf(yi - cur.x)), fabsf(zi - cur.y));
            float d1 = fmaxf(fmaxf(fabsf(xi - vx.y), fabsf(yi - cur.y)), fabsf(zi - cur.z));
            float d2 = fmaxf(fmaxf(fabsf(xi - vx.z), fabsf(yi - cur.z)), fabsf(zi - cur.w));
            float d3 = fmaxf(fmaxf(fabsf(xi - vx.w), fabsf(yi - cur.w)), fabsf(zi - nxt.x));
            d0 = (jb     == i) ? BIGF : d0;
            d1 = (jb + 1 == i) ? BIGF : d1;
            d2 = (jb + 2 == i) ? BIGF : d2;
            d3 = (jb + 3 == i) ? BIGF : d3;
            e0 = fminf(e0, d0); e1 = fminf(e1, d1);
            e2 = fminf(e2, d2); e3 = fminf(e3, d3);
            cur = nxt;
        }
    } else {
        #pragma unroll 2
        for (int jg = 0; jg < CHUNK; jg += 4) {
            float4 nxt = *(const float4*)(sys + jg + 4);
            float4 vx  = *(const float4*)(sxs + jg);
            float d0 = fmaxf(fmaxf(fabsf(xi - vx.x), fabsf(yi - cur.x)), fabsf(zi - cur.y));
            float d1 = fmaxf(fmaxf(fabsf(xi - vx.y), fabsf(yi - cur.y)), fabsf(zi - cur.z));
            float d2 = fmaxf(fmaxf(fabsf(xi - vx.z), fabsf(yi - cur.z)), fabsf(zi - cur.w));
            float d3 = fmaxf(fmaxf(fabsf(xi - vx.w), fabsf(yi - cur.w)), fabsf(zi - nxt.x));
            e0 = fminf(e0, d0); e1 = fminf(e1, d1);
            e2 = fminf(e2, d2); e3 = fminf(e3, d3);
            cur = nxt;
        }
    }
    float ep = fminf(fminf(e0, e1), fminf(e2, e3));
    if (i < N_TE)
        atomicMin(&eps[c * N_TEP + i], __float_as_uint(ep));  // dist>=0: uint order == float order
}

// Pass 2: partial strict-< counts over one j-chunk (diagonal intentionally
// counted: cancels the +1 inside psi(n+1)). Pad slot 5119: sx sentinel kills
// nxy, sys[E_TOT]=BIG kills nyz; the spurious ny hit is subtracted in te_dig.
// grid = (IB, NCH, C)
__global__ __launch_bounds__(256) void te_cnt_kernel(
    const float* __restrict__ seqx, const float* __restrict__ seqy,
    const float* __restrict__ eps, int* __restrict__ cntY,
    int* __restrict__ cntXY, int* __restrict__ cntYZ) {
    __shared__ __align__(16) float sxs[CHUNK];
    __shared__ __align__(16) float sys[CHUNK + 8];
    const int ib = blockIdx.x, k = blockIdx.y, c = blockIdx.z;
    const int j0 = k * CHUNK;
    const float* qx = seqx + c * SEQP + j0;
    const float* qy = seqy + c * SEQP + j0;
    for (int l = threadIdx.x; l < CHUNK; l += 256) sxs[l] = qx[l];
    for (int l = threadIdx.x; l < CHUNK + 8; l += 256) sys[l] = (l <= CHUNK) ? qy[l] : BIGF;
    __syncthreads();

    const int i = ib * 256 + threadIdx.x;
    const float xi = seqx[c * SEQP + i];
    const float yi = seqy[c * SEQP + i];
    const float zi = seqy[c * SEQP + i + 1];
    const float epsi = (i < N_TE) ? eps[c * N_TEP + i] : 0.0f;

    int ny = 0, nxy = 0, nyz = 0;
    float4 cur = *(const float4*)sys;
    #pragma unroll 2
    for (int jg = 0; jg < CHUNK; jg += 4) {
        float4 nxt = *(const float4*)(sys + jg + 4);
        float4 vx  = *(const float4*)(sxs + jg);
        int bx0 = fabsf(xi - vx.x) < epsi, by0 = fabsf(yi - cur.x) < epsi, bz0 = fabsf(zi - cur.y) < epsi;
        int bx1 = fabsf(xi - vx.y) < epsi, by1 = fabsf(yi - cur.y) < epsi, bz1 = fabsf(zi - cur.z) < epsi;
        int bx2 = fabsf(xi - vx.z) < epsi, by2 = fabsf(yi - cur.z) < epsi, bz2 = fabsf(zi - cur.w) < epsi;
        int bx3 = fabsf(xi - vx.w) < epsi, by3 = fabsf(yi - cur.w) < epsi, bz3 = fabsf(zi - nxt.x) < epsi;
        ny  += by0 + by1 + by2 + by3;
        nxy += (bx0 & by0) + (bx1 & by1) + (bx2 & by2) + (bx3 & by3);
        nyz += (by0 & bz0) + (by1 & bz1) + (by2 & bz2) + (by3 & bz3);
        cur = nxt;
    }
    if (i < N_TE) {
        atomicAdd(&cntY[c * N_TEP + i], ny);
        atomicAdd(&cntXY[c * N_TEP + i], nxy);
        atomicAdd(&cntYZ[c * N_TEP + i], nyz);
    }
}

// Pass 3: pad-slot correction + digamma + block-reduce into tes[c].
// grid = (IB, C)
__global__ __launch_bounds__(256) void te_dig_kernel(
    const int* __restrict__ cntY, const int* __restrict__ cntXY,
    const int* __restrict__ cntYZ, const float* __restrict__ eps,
    const float* __restrict__ seqy, float* __restrict__ tes) {
    __shared__ float wsum[4];
    const int c = blockIdx.y;
    const int i = blockIdx.x * 256 + threadIdx.x;
    float local = 0.0f;
    if (i < N_TE) {
        int ny  = cntY[c * N_TEP + i];
        int nxy = cntXY[c * N_TEP + i];
        int nyz = cntYZ[c * N_TEP + i];
        float epsi = eps[c * N_TEP + i];
        float yi = seqy[c * SEQP + i];
        float yt = seqy[c * SEQP + N_TE];   // y value at pad pair slot 5119
        ny -= (fabsf(yi - yt) < epsi) ? 1 : 0;
        local = digammaf_dev((float)ny) - digammaf_dev((float)nxy)
              - digammaf_dev((float)nyz);
    }
    #pragma unroll
    for (int m = 32; m >= 1; m >>= 1) local += __shfl_xor(local, m, 64);
    if ((threadIdx.x & 63) == 0) wsum[threadIdx.x >> 6] = local;
    __syncthreads();
    if (threadIdx.x == 0)
        atomicAdd(&tes[c], wsum[0] + wsum[1] + wsum[2] + wsum[3]);
}

// msg = sigmoid(te_c * h[src][c]); segment-sum into sums[dst][c]
template <int C>
__global__ void agg_kernel(const float* __restrict__ h, const int* __restrict__ ei,
                           const float* __restrict__ tes_accum, float half_scale,
                           float* __restrict__ sums) {
    int idx = blockIdx.x * blockDim.x + threadIdx.x;
    if (idx >= E_TOT * C) return;
    int e = idx / C, c = idx % C;
    int s = (e < N_EDGES) ? ei[e] : (e - N_EDGES);
    int d = (e < N_EDGES) ? ei[N_EDGES + e] : (e - N_EDGES);
    float te = (-0.57721566490153286f + tes_accum[c] * (1.0f / (float)N_TE)) * half_scale;
    float xj = h[s * C + c];
    float m = 1.0f / (1.0f + expf(-te * xj));
    atomicAdd(&sums[d * C + c], m);
}

__global__ void fin1_kernel(const float* __restrict__ sums, const float* __restrict__ cnt,
                            float* __restrict__ h1a) {
    int idx = blockIdx.x * blockDim.x + threadIdx.x;
    if (idx >= N_NODES * HID) return;
    int v = idx / HID;
    float val = sums[idx] / fmaxf(cnt[v], 1.0f);
    h1a[idx] = fmaxf(val, 0.0f);
}

__global__ void gemm2_kernel(const float* __restrict__ h1a, const float* __restrict__ W2,
                             const float* __restrict__ b2, float* __restrict__ h2) {
    int idx = blockIdx.x * blockDim.x + threadIdx.x;
    if (idx >= N_NODES * OUT_CH) return;
    int v = idx / OUT_CH, o = idx % OUT_CH;
    float s = b2[o];
    #pragma unroll
    for (int k = 0; k < HID; ++k) s += h1a[v * HID + k] * W2[o * HID + k];
    h2[idx] = s;
}

__global__ void fin2_kernel(const float* __restrict__ sums2, const float* __restrict__ cnt,
                            float* __restrict__ out) {
    int v = blockIdx.x * blockDim.x + threadIdx.x;
    if (v >= N_NODES) return;
    float c = fmaxf(cnt[v], 1.0f);
    float vals[OUT_CH];
    float mx = -INFINITY;
    #pragma unroll
    for (int o = 0; o < OUT_CH; ++o) {
        vals[o] = sums2[v * OUT_CH + o] / c;
        mx = fmaxf(mx, vals[o]);
    }
    float se = 0.0f;
    #pragma unroll
    for (int o = 0; o < OUT_CH; ++o) se += expf(vals[o] - mx);
    float lse = mx + logf(se);
    #pragma unroll
    for (int o = 0; o < OUT_CH; ++o) out[v * OUT_CH + o] = vals[o] - lse;
}

extern "C" void kernel_launch(void* const* d_in, const int* in_sizes, int n_in,
                              void* d_out, int out_size, void* d_ws, size_t ws_size,
                              hipStream_t stream) {
    const float* x  = (const float*)d_in[0];
    const int*   ei = (const int*)  d_in[1];
    const float* W1 = (const float*)d_in[2];
    const float* b1 = (const float*)d_in[3];
    const float* W2 = (const float*)d_in[4];
    const float* b2 = (const float*)d_in[5];
    float* out = (float*)d_out;

    float* w = (float*)d_ws;
    size_t o = 0;
    // ---- zeroed region (atomic accumulators) ----
    float* sums1 = w + o; o += N_NODES * HID;      // 16384
    float* sums2 = w + o; o += N_NODES * OUT_CH;   // 7168
    float* cdeg  = w + o; o += N_NODES;            // 1024
    float* tes1  = w + o; o += 16;
    float* tes2  = w + o; o += 16;
    int* cY1  = (int*)(w + o); o += HID * N_TEP;
    int* cXY1 = (int*)(w + o); o += HID * N_TEP;
    int* cYZ1 = (int*)(w + o); o += HID * N_TEP;
    int* cY2  = (int*)(w + o); o += OUT_CH * N_TEP;
    int* cXY2 = (int*)(w + o); o += OUT_CH * N_TEP;
    int* cYZ2 = (int*)(w + o); o += OUT_CH * N_TEP;
    const size_t zero_elems = o;
    // ---- non-zeroed region ----
    float* h1    = w + o; o += N_NODES * HID;
    float* h1a   = w + o; o += N_NODES * HID;
    float* h2    = w + o; o += N_NODES * OUT_CH;
    float* seqx1 = w + o; o += HID * SEQP;
    float* seqy1 = w + o; o += HID * SEQP;
    float* seqx2 = w + o; o += OUT_CH * SEQP;
    float* seqy2 = w + o; o += OUT_CH * SEQP;
    float* eps1  = w + o; o += HID * N_TEP;
    float* eps2  = w + o; o += OUT_CH * N_TEP;    // contiguous with eps1

    hipMemsetAsync(d_ws, 0, zero_elems * sizeof(float), stream);
    const int n_eps = (HID + OUT_CH) * N_TEP;
    eps_init_kernel<<<(n_eps + 255) / 256, 256, 0, stream>>>(eps1, n_eps);

    gemm1_kernel<<<N_NODES, 256, 0, stream>>>(x, W1, b1, h1);
    cnt_kernel<<<(E_TOT + 255) / 256, 256, 0, stream>>>(ei, cdeg);

    // ---- layer 1 TE ----
    seq_build_kernel<HID><<<(E_TOT + 256) / 256, 256, 0, stream>>>(h1, ei, seqx1, seqy1);
    te_eps_kernel<<<dim3(IB, NCH, HID), 256, 0, stream>>>(seqx1, seqy1, (unsigned int*)eps1);
    te_cnt_kernel<<<dim3(IB, NCH, HID), 256, 0, stream>>>(seqx1, seqy1, eps1, cY1, cXY1, cYZ1);
    te_dig_kernel<<<dim3(IB, HID), 256, 0, stream>>>(cY1, cXY1, cYZ1, eps1, seqy1, tes1);
    agg_kernel<HID><<<(E_TOT * HID + 255) / 256, 256, 0, stream>>>(h1, ei, tes1, 1.0f, sums1);
    fin1_kernel<<<(N_NODES * HID + 255) / 256, 256, 0, stream>>>(sums1, cdeg, h1a);

    // ---- layer 2 ----
    gemm2_kernel<<<(N_NODES * OUT_CH + 255) / 256, 256, 0, stream>>>(h1a, W2, b2, h2);
    seq_build_kernel<OUT_CH><<<(E_TOT + 256) / 256, 256, 0, stream>>>(h2, ei, seqx2, seqy2);
    te_eps_kernel<<<dim3(IB, NCH, OUT_CH), 256, 0, stream>>>(seqx2, seqy2, (unsigned int*)eps2);
    te_cnt_kernel<<<dim3(IB, NCH, OUT_CH), 256, 0, stream>>>(seqx2, seqy2, eps2, cY2, cXY2, cYZ2);
    te_dig_kernel<<<dim3(IB, OUT_CH), 256, 0, stream>>>(cY2, cXY2, cYZ2, eps2, seqy2, tes2);
    agg_kernel<OUT_CH><<<(E_TOT * OUT_CH + 255) / 256, 256, 0, stream>>>(h2, ei, tes2, 0.5f, sums2);
    fin2_kernel<<<(N_NODES + 255) / 256, 256, 0, stream>>>(sums2, cdeg, out);
}